// Round 17
// baseline (24.534 us; speedup 1.0000x reference)
//
#include <hip/hip_runtime.h>
#include <hip/hip_fp16.h>

typedef _Float16 half2_t __attribute__((ext_vector_type(2)));

// cvt_pkrtz returns __fp16x2; bit-cast to our half2_t (same bits)
__device__ __forceinline__ half2_t pkrtz(float lo, float hi) {
    return __builtin_bit_cast(half2_t, __builtin_amdgcn_cvt_pkrtz(lo, hi));
}

template<int CTRL>
__device__ __forceinline__ float dpp_add_step(float x) {
    const int p = __builtin_amdgcn_update_dpp(
        0, __builtin_bit_cast(int, x), CTRL, 0xf, 0xf, true);
    return x + __builtin_bit_cast(float, p);
}

// sum across the 8 lanes of a half-group (lanes [8m, 8m+8))
__device__ __forceinline__ float dpp_reduce8(float a) {
    a = dpp_add_step<0xB1>(a);   // quad_perm:[1,0,3,2]  xor 1
    a = dpp_add_step<0x4E>(a);   // quad_perm:[2,3,0,1]  xor 2
    a = dpp_add_step<0x141>(a);  // row_half_mirror   == xor 4 once quad-uniform
    return a;
}

// fused q.(k+se) on fp16 pairs: 4 pk_add + 4 fdot2
__device__ __forceinline__ float dot8_kse_h(
    const half2_t k0, const half2_t k1, const half2_t k2, const half2_t k3,
    const uint4 eu, const half2_t qh[4])
{
    const half2_t t0 = k0 + __builtin_bit_cast(half2_t, eu.x);
    const half2_t t1 = k1 + __builtin_bit_cast(half2_t, eu.y);
    const half2_t t2 = k2 + __builtin_bit_cast(half2_t, eu.z);
    const half2_t t3 = k3 + __builtin_bit_cast(half2_t, eu.w);
    float a = __builtin_amdgcn_fdot2(qh[0], t0, 0.f, false);
    a = __builtin_amdgcn_fdot2(qh[1], t1, a, false);
    a = __builtin_amdgcn_fdot2(qh[2], t2, a, false);
    a = __builtin_amdgcn_fdot2(qh[3], t3, a, false);
    return a;
}

#define WROWS 128  // LDS window rows: [base-64, base+64), 64 queries/block
#define L2E 1.44269504f

constexpr int NEARO[10] = {1, 3, 4, 13, 15, 21, 23, 28, 48, 64};  // idx 0..9
constexpr int FARO[6]   = {96, 192, 384, 512, 768, 1024};         // idx 10..15

// Fused no-max softmax (scores ~N(0,1)+bias, exp cannot overflow fp32).
// Lane map: 16-lane group g handles queries base+2g (lanes 0-7) and +1
// (lanes 8-15); each lane owns dims [d8, d8+8) of its own query.
// Schedule (r15's, best measured): issue fk -> near scores (hide fk) ->
// far scores (fk dies) -> issue fv -> near V (hide fv) -> far V.
template<bool SAFE>
__device__ __forceinline__ void run_block(
    const float* __restrict__ kh, const float* __restrict__ vh,
    const float* __restrict__ pb, const int h,
    const __half* ksh, const __half* vsh, const __half* se_sh,
    const half2_t qh[4],
    const int n, const int ql, const int d8,
    float4& o0, float4& o1, half2_t o16[4], float& l)
{
    constexpr float SC = 0.125f * L2E; // (1/sqrt(64)) * log2(e)

    float pw[16];

    // ---- issue all 6 far k loads (batched: one latency exposure) ----
    float4 fk0[6], fk1[6];
#pragma unroll
    for (int t = 0; t < 6; ++t) {
        const int idx  = n - FARO[t];
        const int idxc = SAFE ? (idx < 0 ? 0 : idx) : idx;
        const float4* kp = (const float4*)(kh + ((size_t)idxc << 6) + d8);
        fk0[t] = kp[0]; fk1[t] = kp[1];
    }

    // ---- near scores from LDS while far k flies ----
#pragma unroll
    for (int t = 0; t < 10; ++t) {
        const int off = NEARO[t];
        const int row = ql + 64 - off;     // in [0, 127]
        const uint4 ku = *(const uint4*)&ksh[(row << 6) + d8];
        const uint4 eu = *(const uint4*)&se_sh[(t << 6) + d8];
        float a = dot8_kse_h(__builtin_bit_cast(half2_t, ku.x),
                             __builtin_bit_cast(half2_t, ku.y),
                             __builtin_bit_cast(half2_t, ku.z),
                             __builtin_bit_cast(half2_t, ku.w), eu, qh);
        a = dpp_reduce8(a);
        float p = exp2f(fmaf(a, SC, pb[(t << 4) + h] * L2E));
        if (SAFE) p = (n - off >= 0) ? p : 0.f;
        pw[t] = p;
    }

    // ---- far scores (k -> fp16, fused +se); fk dies here ----
#pragma unroll
    for (int t = 0; t < 6; ++t) {
        const int i = t + 10;
        const uint4 eu = *(const uint4*)&se_sh[(i << 6) + d8];
        float a = dot8_kse_h(pkrtz(fk0[t].x, fk0[t].y),
                             pkrtz(fk0[t].z, fk0[t].w),
                             pkrtz(fk1[t].x, fk1[t].y),
                             pkrtz(fk1[t].z, fk1[t].w), eu, qh);
        a = dpp_reduce8(a);
        float p = exp2f(fmaf(a, SC, pb[(i << 4) + h] * L2E));
        if (SAFE) p = (n - FARO[t] >= 0) ? p : 0.f;
        pw[i] = p;
    }

    l = ((pw[0] + pw[1]) + (pw[2] + pw[3])) + ((pw[4] + pw[5]) + (pw[6] + pw[7]))
      + ((pw[8] + pw[9]) + (pw[10] + pw[11])) + ((pw[12] + pw[13]) + (pw[14] + pw[15]));

    // ---- issue all 6 far v loads (fk regs dead; fv flies under near V) ----
    float4 fv0[6], fv1[6];
#pragma unroll
    for (int t = 0; t < 6; ++t) {
        const int idx  = n - FARO[t];
        const int idxc = SAFE ? (idx < 0 ? 0 : idx) : idx;
        const float4* vp = (const float4*)(vh + ((size_t)idxc << 6) + d8);
        fv0[t] = vp[0]; fv1[t] = vp[1];
    }

    // ---- near V from LDS (fp16 pk_fma) ----
#pragma unroll
    for (int t = 0; t < 10; ++t) {
        const int row = ql + 64 - NEARO[t];
        const uint4 vu = *(const uint4*)&vsh[(row << 6) + d8];
        const _Float16 ph = (_Float16)pw[t];
        const half2_t pwh = {ph, ph};
        o16[0] = __builtin_bit_cast(half2_t, vu.x) * pwh + o16[0];
        o16[1] = __builtin_bit_cast(half2_t, vu.y) * pwh + o16[1];
        o16[2] = __builtin_bit_cast(half2_t, vu.z) * pwh + o16[2];
        o16[3] = __builtin_bit_cast(half2_t, vu.w) * pwh + o16[3];
    }

    // ---- far V fp32 accumulate ----
#pragma unroll
    for (int t = 0; t < 6; ++t) {
        const float p = pw[t + 10];
        o0.x += p*fv0[t].x; o0.y += p*fv0[t].y; o0.z += p*fv0[t].z; o0.w += p*fv0[t].w;
        o1.x += p*fv1[t].x; o1.y += p*fv1[t].y; o1.z += p*fv1[t].z; o1.w += p*fv1[t].w;
    }
}

__global__ __launch_bounds__(512, 4) void dsqg_attn_kernel(
    const float* __restrict__ q, const float* __restrict__ k,
    const float* __restrict__ v, const float* __restrict__ pb,
    const float* __restrict__ se, float* __restrict__ out)
{
    __shared__ __half ksh[WROWS * 64]; // window rows [base-64, base+64), fp16
    __shared__ __half vsh[WROWS * 64];
    __shared__ __half se_sh[16 * 64];  // scale_embed table, fp16

    // XCD-aware head-major swizzle: 1024 blocks, XCD x owns logical blocks
    // [x*128, x*128+128) = heads {2x, 2x+1} in ascending query order.
    const int p   = blockIdx.x;
    const int lb_ = ((p & 7) << 7) + (p >> 3);
    const int h   = lb_ >> 6;                       // uniform -> SGPR
    const int nb  = lb_ & 63;
    const int base = nb << 6;                       // 64 queries per block

    const int g   = threadIdx.x >> 4;               // group 0..31
    const int j   = threadIdx.x & 15;
    const int sub = j >> 3;                         // 0: query A, 1: query B
    const int d8  = (j & 7) << 3;                   // dim start, lane owns 8 dims
    const int ql  = (g << 1) + sub;                 // local query 0..63
    const int n   = base + ql;
    const size_t hb = (size_t)h << 18;              // h * 4096 * 64

    const float* kh = k + hb;
    const float* vh = v + hb;

    // q: 8 dims of this lane's query (issued early, overlaps staging)
    const float4* qp = (const float4*)(q + hb + ((size_t)n << 6) + d8);
    const float4 q0 = qp[0], q1 = qp[1];

    // stage k/v window [base-64, base+64) as fp16: lane owns 8 floats/row,
    // 2 iters x 64 rows, b128 LDS writes
    {
        const int r64 = threadIdx.x >> 3;           // 0..63
        const int c8  = (threadIdx.x & 7) << 3;     // float col 0..56
#pragma unroll
        for (int it = 0; it < 2; ++it) {
            const int sr = (it << 6) + r64;         // 0..127
            int gr = base - 64 + sr;
            gr = gr < 0 ? 0 : gr;
            const float4* kp = (const float4*)(kh + ((size_t)gr << 6) + c8);
            const float4 kf0 = kp[0], kf1 = kp[1];
            const float4* vp = (const float4*)(vh + ((size_t)gr << 6) + c8);
            const float4 vf0 = vp[0], vf1 = vp[1];
            union { half2_t h2[4]; uint4 u; } pk, pv;
            pk.h2[0] = pkrtz(kf0.x, kf0.y);
            pk.h2[1] = pkrtz(kf0.z, kf0.w);
            pk.h2[2] = pkrtz(kf1.x, kf1.y);
            pk.h2[3] = pkrtz(kf1.z, kf1.w);
            pv.h2[0] = pkrtz(vf0.x, vf0.y);
            pv.h2[1] = pkrtz(vf0.z, vf0.w);
            pv.h2[2] = pkrtz(vf1.x, vf1.y);
            pv.h2[3] = pkrtz(vf1.z, vf1.w);
            *(uint4*)&ksh[(sr << 6) + c8] = pk.u;
            *(uint4*)&vsh[(sr << 6) + c8] = pv.u;
        }
    }
    // stage se as fp16: threads 0..255, thread t covers floats [4t, 4t+4)
    if (threadIdx.x < 256) {
        const float4 sf = *(const float4*)(se + (threadIdx.x << 2));
        union { half2_t h2[2]; uint2 u; } ps;
        ps.h2[0] = pkrtz(sf.x, sf.y);
        ps.h2[1] = pkrtz(sf.z, sf.w);
        *(uint2*)&se_sh[threadIdx.x << 2] = ps.u;
    }

    // q in fp16 for the fdot2 paths (fp32 q dies here -> fewer live regs)
    half2_t qh[4];
    qh[0] = pkrtz(q0.x, q0.y);
    qh[1] = pkrtz(q0.z, q0.w);
    qh[2] = pkrtz(q1.x, q1.y);
    qh[3] = pkrtz(q1.z, q1.w);

    __syncthreads();

    float l = 0.f;
    float4 o0 = make_float4(0.f, 0.f, 0.f, 0.f);
    float4 o1 = make_float4(0.f, 0.f, 0.f, 0.f);
    half2_t o16[4] = {half2_t{0, 0}, half2_t{0, 0}, half2_t{0, 0}, half2_t{0, 0}};

    if (nb >= 16) {
        // base >= 1024: all 16 offsets valid for every query in the block
        run_block<false>(kh, vh, pb, h, ksh, vsh, se_sh, qh, n, ql, d8, o0, o1, o16, l);
    } else {
        run_block<true>(kh, vh, pb, h, ksh, vsh, se_sh, qh, n, ql, d8, o0, o1, o16, l);
    }

    // merge fp16 near-accumulator into fp32
    {
        const float2 f0 = __half22float2(__builtin_bit_cast(__half2, o16[0]));
        const float2 f1 = __half22float2(__builtin_bit_cast(__half2, o16[1]));
        const float2 f2 = __half22float2(__builtin_bit_cast(__half2, o16[2]));
        const float2 f3 = __half22float2(__builtin_bit_cast(__half2, o16[3]));
        o0.x += f0.x; o0.y += f0.y; o0.z += f1.x; o0.w += f1.y;
        o1.x += f2.x; o1.y += f2.y; o1.z += f3.x; o1.w += f3.y;
    }

    const float inv = (l > 0.f) ? 1.f / l : 0.f;    // l==0 only at n==0
    o0.x *= inv; o0.y *= inv; o0.z *= inv; o0.w *= inv;
    o1.x *= inv; o1.y *= inv; o1.z *= inv; o1.w *= inv;
    float4* op = (float4*)(out + hb + ((size_t)n << 6) + d8);
    op[0] = o0; op[1] = o1;
}

extern "C" void kernel_launch(void* const* d_in, const int* in_sizes, int n_in,
                              void* d_out, int out_size, void* d_ws, size_t ws_size,
                              hipStream_t stream) {
    const float* q  = (const float*)d_in[0];
    const float* k  = (const float*)d_in[1];
    const float* v  = (const float*)d_in[2];
    const float* pb = (const float*)d_in[3]; // (16 offsets, 16 heads)
    const float* se = (const float*)d_in[4]; // (16 offsets, 64 dims)
    float* out = (float*)d_out;

    dim3 grid(1024);
    dim3 block(512);
    dsqg_attn_kernel<<<grid, block, 0, stream>>>(q, k, v, pb, se, out);
}

// Round 18
// 21.995 us; speedup vs baseline: 1.1155x; 1.1155x over previous
//
#include <hip/hip_runtime.h>
#include <hip/hip_fp16.h>

typedef _Float16 half2_t __attribute__((ext_vector_type(2)));

// cvt_pkrtz returns __fp16x2; bit-cast to our half2_t (same bits)
__device__ __forceinline__ half2_t pkrtz(float lo, float hi) {
    return __builtin_bit_cast(half2_t, __builtin_amdgcn_cvt_pkrtz(lo, hi));
}

template<int CTRL>
__device__ __forceinline__ float dpp_add_step(float x) {
    const int p = __builtin_amdgcn_update_dpp(
        0, __builtin_bit_cast(int, x), CTRL, 0xf, 0xf, true);
    return x + __builtin_bit_cast(float, p);
}

// sum across the 8 lanes of a half-group (lanes [8m, 8m+8))
__device__ __forceinline__ float dpp_reduce8(float a) {
    a = dpp_add_step<0xB1>(a);   // quad_perm:[1,0,3,2]  xor 1
    a = dpp_add_step<0x4E>(a);   // quad_perm:[2,3,0,1]  xor 2
    a = dpp_add_step<0x141>(a);  // row_half_mirror   == xor 4 once quad-uniform
    return a;
}

// fused q.(k+se) on fp16 pairs: 4 pk_add + 4 fdot2
__device__ __forceinline__ float dot8_kse_h(
    const half2_t k0, const half2_t k1, const half2_t k2, const half2_t k3,
    const uint4 eu, const half2_t qh[4])
{
    const half2_t t0 = k0 + __builtin_bit_cast(half2_t, eu.x);
    const half2_t t1 = k1 + __builtin_bit_cast(half2_t, eu.y);
    const half2_t t2 = k2 + __builtin_bit_cast(half2_t, eu.z);
    const half2_t t3 = k3 + __builtin_bit_cast(half2_t, eu.w);
    float a = __builtin_amdgcn_fdot2(qh[0], t0, 0.f, false);
    a = __builtin_amdgcn_fdot2(qh[1], t1, a, false);
    a = __builtin_amdgcn_fdot2(qh[2], t2, a, false);
    a = __builtin_amdgcn_fdot2(qh[3], t3, a, false);
    return a;
}

#define WROWS 96   // LDS window rows: [base-64, base+32)
#define L2E 1.44269504f

constexpr int NEARO[10] = {1, 3, 4, 13, 15, 21, 23, 28, 48, 64};  // idx 0..9
constexpr int FARO[6]   = {96, 192, 384, 512, 768, 1024};         // idx 10..15

// Fused no-max softmax (scores ~N(0,1)+bias, exp cannot overflow fp32).
// Lane map: 16-lane group g handles queries base+2g (lanes 0-7) and +1
// (lanes 8-15); each lane owns dims [d8, d8+8) of its own query.
// Schedule (best measured, r15): issue fk -> near scores (hide fk) ->
// far scores (fk dies) -> issue fv -> near V (hide fv) -> far V.
// fk and fv never coexist: peak ~95 VGPR, no spill at the (256,4) cap.
template<bool SAFE>
__device__ __forceinline__ void run_block(
    const float* __restrict__ kh, const float* __restrict__ vh,
    const float* __restrict__ pb, const int h,
    const __half* ksh, const __half* vsh, const __half* se_sh,
    const half2_t qh[4],
    const int n, const int ql, const int d8,
    float4& o0, float4& o1, half2_t o16[4], float& l)
{
    constexpr float SC = 0.125f * L2E; // (1/sqrt(64)) * log2(e)

    float pw[16];

    // ---- issue all 6 far k loads (batched: one latency exposure) ----
    float4 fk0[6], fk1[6];
#pragma unroll
    for (int t = 0; t < 6; ++t) {
        const int idx  = n - FARO[t];
        const int idxc = SAFE ? (idx < 0 ? 0 : idx) : idx;
        const float4* kp = (const float4*)(kh + ((size_t)idxc << 6) + d8);
        fk0[t] = kp[0]; fk1[t] = kp[1];
    }

    // ---- near scores from LDS while far k flies ----
#pragma unroll
    for (int t = 0; t < 10; ++t) {
        const int off = NEARO[t];
        const int row = ql + 64 - off;     // in [0, 95]
        const uint4 ku = *(const uint4*)&ksh[(row << 6) + d8];
        const uint4 eu = *(const uint4*)&se_sh[(t << 6) + d8];
        float a = dot8_kse_h(__builtin_bit_cast(half2_t, ku.x),
                             __builtin_bit_cast(half2_t, ku.y),
                             __builtin_bit_cast(half2_t, ku.z),
                             __builtin_bit_cast(half2_t, ku.w), eu, qh);
        a = dpp_reduce8(a);
        float p = exp2f(fmaf(a, SC, pb[(t << 4) + h] * L2E));
        if (SAFE) p = (n - off >= 0) ? p : 0.f;
        pw[t] = p;
    }

    // ---- far scores (k -> fp16, fused +se); fk dies here ----
#pragma unroll
    for (int t = 0; t < 6; ++t) {
        const int i = t + 10;
        const uint4 eu = *(const uint4*)&se_sh[(i << 6) + d8];
        float a = dot8_kse_h(pkrtz(fk0[t].x, fk0[t].y),
                             pkrtz(fk0[t].z, fk0[t].w),
                             pkrtz(fk1[t].x, fk1[t].y),
                             pkrtz(fk1[t].z, fk1[t].w), eu, qh);
        a = dpp_reduce8(a);
        float p = exp2f(fmaf(a, SC, pb[(i << 4) + h] * L2E));
        if (SAFE) p = (n - FARO[t] >= 0) ? p : 0.f;
        pw[i] = p;
    }

    l = ((pw[0] + pw[1]) + (pw[2] + pw[3])) + ((pw[4] + pw[5]) + (pw[6] + pw[7]))
      + ((pw[8] + pw[9]) + (pw[10] + pw[11])) + ((pw[12] + pw[13]) + (pw[14] + pw[15]));

    // ---- issue all 6 far v loads (fk regs dead; fv flies under near V) ----
    float4 fv0[6], fv1[6];
#pragma unroll
    for (int t = 0; t < 6; ++t) {
        const int idx  = n - FARO[t];
        const int idxc = SAFE ? (idx < 0 ? 0 : idx) : idx;
        const float4* vp = (const float4*)(vh + ((size_t)idxc << 6) + d8);
        fv0[t] = vp[0]; fv1[t] = vp[1];
    }

    // ---- near V from LDS (fp16 pk_fma) ----
#pragma unroll
    for (int t = 0; t < 10; ++t) {
        const int row = ql + 64 - NEARO[t];
        const uint4 vu = *(const uint4*)&vsh[(row << 6) + d8];
        const _Float16 ph = (_Float16)pw[t];
        const half2_t pwh = {ph, ph};
        o16[0] = __builtin_bit_cast(half2_t, vu.x) * pwh + o16[0];
        o16[1] = __builtin_bit_cast(half2_t, vu.y) * pwh + o16[1];
        o16[2] = __builtin_bit_cast(half2_t, vu.z) * pwh + o16[2];
        o16[3] = __builtin_bit_cast(half2_t, vu.w) * pwh + o16[3];
    }

    // ---- far V fp32 accumulate (fv landed during the compute above) ----
#pragma unroll
    for (int t = 0; t < 6; ++t) {
        const float p = pw[t + 10];
        o0.x += p*fv0[t].x; o0.y += p*fv0[t].y; o0.z += p*fv0[t].z; o0.w += p*fv0[t].w;
        o1.x += p*fv1[t].x; o1.y += p*fv1[t].y; o1.z += p*fv1[t].z; o1.w += p*fv1[t].w;
    }
}

__global__ __launch_bounds__(256, 4) void dsqg_attn_kernel(
    const float* __restrict__ q, const float* __restrict__ k,
    const float* __restrict__ v, const float* __restrict__ pb,
    const float* __restrict__ se, float* __restrict__ out)
{
    __shared__ __half ksh[WROWS * 64]; // window rows [base-64, base+32), fp16
    __shared__ __half vsh[WROWS * 64];
    __shared__ __half se_sh[16 * 64];  // scale_embed table, fp16

    // XCD-aware head-major swizzle (XCD x owns heads {2x, 2x+1}, ascending n).
    const int p   = blockIdx.x;
    const int lb_ = ((p & 7) << 8) + (p >> 3);
    const int h   = lb_ >> 7;                       // uniform -> SGPR
    const int nb  = lb_ & 127;
    const int base = nb << 5;

    const int g   = threadIdx.x >> 4;               // group 0..15
    const int j   = threadIdx.x & 15;
    const int sub = j >> 3;                         // 0: query A, 1: query B
    const int d8  = (j & 7) << 3;                   // dim start, lane owns 8 dims
    const int ql  = (g << 1) + sub;                 // local query 0..31
    const int n   = base + ql;
    const size_t hb = (size_t)h << 18;              // h * 4096 * 64

    const float* kh = k + hb;
    const float* vh = v + hb;

    // q: 8 dims of this lane's query (issued early, overlaps staging)
    const float4* qp = (const float4*)(q + hb + ((size_t)n << 6) + d8);
    const float4 q0 = qp[0], q1 = qp[1];

    // stage k/v window [base-64, base+32) as fp16: lane owns 8 floats/row,
    // 3 iters x 32 rows, b128 LDS writes
    {
        const int r32 = threadIdx.x >> 3;           // 0..31
        const int c8  = (threadIdx.x & 7) << 3;     // float col 0..56
#pragma unroll
        for (int it = 0; it < 3; ++it) {
            const int sr = (it << 5) + r32;         // 0..95
            int gr = base - 64 + sr;
            gr = gr < 0 ? 0 : gr;
            const float4* kp = (const float4*)(kh + ((size_t)gr << 6) + c8);
            const float4 kf0 = kp[0], kf1 = kp[1];
            const float4* vp = (const float4*)(vh + ((size_t)gr << 6) + c8);
            const float4 vf0 = vp[0], vf1 = vp[1];
            union { half2_t h2[4]; uint4 u; } pk, pv;
            pk.h2[0] = pkrtz(kf0.x, kf0.y);
            pk.h2[1] = pkrtz(kf0.z, kf0.w);
            pk.h2[2] = pkrtz(kf1.x, kf1.y);
            pk.h2[3] = pkrtz(kf1.z, kf1.w);
            pv.h2[0] = pkrtz(vf0.x, vf0.y);
            pv.h2[1] = pkrtz(vf0.z, vf0.w);
            pv.h2[2] = pkrtz(vf1.x, vf1.y);
            pv.h2[3] = pkrtz(vf1.z, vf1.w);
            *(uint4*)&ksh[(sr << 6) + c8] = pk.u;
            *(uint4*)&vsh[(sr << 6) + c8] = pv.u;
        }
    }
    // stage se as fp16: thread t covers floats [4t, 4t+4)
    {
        const float4 sf = *(const float4*)(se + (threadIdx.x << 2));
        union { half2_t h2[2]; uint2 u; } ps;
        ps.h2[0] = pkrtz(sf.x, sf.y);
        ps.h2[1] = pkrtz(sf.z, sf.w);
        *(uint2*)&se_sh[threadIdx.x << 2] = ps.u;
    }

    // q in fp16 for the fdot2 paths (fp32 q dies here -> fewer live regs)
    half2_t qh[4];
    qh[0] = pkrtz(q0.x, q0.y);
    qh[1] = pkrtz(q0.z, q0.w);
    qh[2] = pkrtz(q1.x, q1.y);
    qh[3] = pkrtz(q1.z, q1.w);

    __syncthreads();

    float l = 0.f;
    float4 o0 = make_float4(0.f, 0.f, 0.f, 0.f);
    float4 o1 = make_float4(0.f, 0.f, 0.f, 0.f);
    half2_t o16[4] = {half2_t{0, 0}, half2_t{0, 0}, half2_t{0, 0}, half2_t{0, 0}};

    if (nb >= 32) {
        run_block<false>(kh, vh, pb, h, ksh, vsh, se_sh, qh, n, ql, d8, o0, o1, o16, l);
    } else {
        run_block<true>(kh, vh, pb, h, ksh, vsh, se_sh, qh, n, ql, d8, o0, o1, o16, l);
    }

    // merge fp16 near-accumulator into fp32
    {
        const float2 f0 = __half22float2(__builtin_bit_cast(__half2, o16[0]));
        const float2 f1 = __half22float2(__builtin_bit_cast(__half2, o16[1]));
        const float2 f2 = __half22float2(__builtin_bit_cast(__half2, o16[2]));
        const float2 f3 = __half22float2(__builtin_bit_cast(__half2, o16[3]));
        o0.x += f0.x; o0.y += f0.y; o0.z += f1.x; o0.w += f1.y;
        o1.x += f2.x; o1.y += f2.y; o1.z += f3.x; o1.w += f3.y;
    }

    const float inv = (l > 0.f) ? 1.f / l : 0.f;    // l==0 only at n==0
    o0.x *= inv; o0.y *= inv; o0.z *= inv; o0.w *= inv;
    o1.x *= inv; o1.y *= inv; o1.z *= inv; o1.w *= inv;
    float4* op = (float4*)(out + hb + ((size_t)n << 6) + d8);
    op[0] = o0; op[1] = o1;
}

extern "C" void kernel_launch(void* const* d_in, const int* in_sizes, int n_in,
                              void* d_out, int out_size, void* d_ws, size_t ws_size,
                              hipStream_t stream) {
    const float* q  = (const float*)d_in[0];
    const float* k  = (const float*)d_in[1];
    const float* v  = (const float*)d_in[2];
    const float* pb = (const float*)d_in[3]; // (16 offsets, 16 heads)
    const float* se = (const float*)d_in[4]; // (16 offsets, 64 dims)
    float* out = (float*)d_out;

    dim3 grid(2048);
    dim3 block(256);
    dsqg_attn_kernel<<<grid, block, 0, stream>>>(q, k, v, pb, se, out);
}